// Round 1
// baseline (491.223 us; speedup 1.0000x reference)
//
#include <hip/hip_runtime.h>

// ---------------------------------------------------------------------------
// MultiHeadCausalAttention: B=2, T=4096, C=768, H=12, Dh=64
// bf16 MFMA pipeline: cvt -> QKV GEMM -> V transpose -> flash attn -> out GEMM
// ---------------------------------------------------------------------------

#define NHEADS 12
#define DHEAD  64
#define TSEQ   4096
#define BATCH  2
#define CMODEL 768
#define MTOT   (BATCH * TSEQ)   /* 8192 */
#define NQKV   (3 * CMODEL)     /* 2304 */

typedef __attribute__((ext_vector_type(8))) short s16x8;
typedef __attribute__((ext_vector_type(4))) float f32x4;
typedef __attribute__((ext_vector_type(4))) unsigned short u16x4;

__device__ __forceinline__ unsigned short f2bf(float f) {
    unsigned u = __builtin_bit_cast(unsigned, f);
    u += 0x7fffu + ((u >> 16) & 1u);   // round-to-nearest-even
    return (unsigned short)(u >> 16);
}

// --------------------------- fp32 -> bf16 cvt ------------------------------
__global__ __launch_bounds__(256) void cvt_bf16_kernel(
    const float* __restrict__ src, unsigned short* __restrict__ dst, int n4)
{
    int i = blockIdx.x * 256 + threadIdx.x;
    if (i < n4) {
        f32x4 v = ((const f32x4*)src)[i];
        u16x4 o;
        o.x = f2bf(v.x); o.y = f2bf(v.y); o.z = f2bf(v.z); o.w = f2bf(v.w);
        ((u16x4*)dst)[i] = o;
    }
}

// --------------------------- QKV projection GEMM ---------------------------
// C[m,n] = sum_k A[m,k] * Bw[n,k] + bias[n]; scatter to Q/K/V [B,H,T,Dh] bf16.
// Q gets pre-scaled by 1/sqrt(Dh) = 0.125.
__global__ __launch_bounds__(256) void gemm_qkv_kernel(
    const unsigned short* __restrict__ A,    // [8192][768] bf16 (x)
    const unsigned short* __restrict__ Bw,   // [2304][768] bf16 (w_qkv)
    const float* __restrict__ bias,          // [2304]
    unsigned short* __restrict__ Qb,
    unsigned short* __restrict__ Kb,
    unsigned short* __restrict__ Vb)
{
    __shared__ unsigned short sA[64][72];
    __shared__ unsigned short sB[64][72];
    const int n0 = blockIdx.x * 64;
    const int m0 = blockIdx.y * 64;
    const int tid = threadIdx.x;
    const int w = tid >> 6, l = tid & 63, g = l >> 4, l15 = l & 15;
    const int row0 = tid >> 3, cg0 = tid & 7;

    f32x4 acc[4];
#pragma unroll
    for (int nt = 0; nt < 4; nt++) acc[nt] = (f32x4){0.f, 0.f, 0.f, 0.f};

    for (int k0 = 0; k0 < 768; k0 += 64) {
        *(s16x8*)&sA[row0][cg0 * 8]      = *(const s16x8*)&A[(m0 + row0) * 768 + k0 + cg0 * 8];
        *(s16x8*)&sA[row0 + 32][cg0 * 8] = *(const s16x8*)&A[(m0 + row0 + 32) * 768 + k0 + cg0 * 8];
        *(s16x8*)&sB[row0][cg0 * 8]      = *(const s16x8*)&Bw[(n0 + row0) * 768 + k0 + cg0 * 8];
        *(s16x8*)&sB[row0 + 32][cg0 * 8] = *(const s16x8*)&Bw[(n0 + row0 + 32) * 768 + k0 + cg0 * 8];
        __syncthreads();
#pragma unroll
        for (int ks = 0; ks < 2; ks++) {
            s16x8 af = *(const s16x8*)&sA[w * 16 + l15][ks * 32 + g * 8];
#pragma unroll
            for (int nt = 0; nt < 4; nt++) {
                s16x8 bf = *(const s16x8*)&sB[nt * 16 + l15][ks * 32 + g * 8];
                acc[nt] = __builtin_amdgcn_mfma_f32_16x16x32_bf16(af, bf, acc[nt], 0, 0, 0);
            }
        }
        __syncthreads();
    }

#pragma unroll
    for (int nt = 0; nt < 4; nt++) {
        int n = n0 + nt * 16 + l15;
        float bv = bias[n];
        int three = n / 768;
        int hh = (n - three * 768) >> 6;
        int dh = n & 63;
        unsigned short* dst = (three == 0) ? Qb : ((three == 1) ? Kb : Vb);
        float scale = (three == 0) ? 0.125f : 1.0f;
#pragma unroll
        for (int r = 0; r < 4; r++) {
            int m = m0 + w * 16 + g * 4 + r;
            int b = m >> 12, t = m & 4095;
            float v = (acc[nt][r] + bv) * scale;
            dst[(((b * NHEADS + hh) * TSEQ + t) * DHEAD) + dh] = f2bf(v);
        }
    }
}

// --------------------------- V transpose -----------------------------------
// Vb [bh][t][dh] -> Vt [bh][dh][t]
__global__ __launch_bounds__(256) void transpose_v_kernel(
    const unsigned short* __restrict__ Vb, unsigned short* __restrict__ Vt)
{
    __shared__ unsigned short sT[64][72];
    const int bh = blockIdx.y;
    const int t0 = blockIdx.x * 64;
    const int tid = threadIdx.x;
    const int row0 = tid >> 3, cg0 = tid & 7;

    const unsigned short* src = Vb + ((size_t)bh * TSEQ + t0) * DHEAD;
    *(s16x8*)&sT[row0][cg0 * 8]      = *(const s16x8*)&src[row0 * DHEAD + cg0 * 8];
    *(s16x8*)&sT[row0 + 32][cg0 * 8] = *(const s16x8*)&src[(row0 + 32) * DHEAD + cg0 * 8];
    __syncthreads();

    unsigned short* dst = Vt + (size_t)bh * DHEAD * TSEQ + t0;
#pragma unroll
    for (int p = 0; p < 2; p++) {
        int dh = row0 + p * 32;
        s16x8 o;
#pragma unroll
        for (int j = 0; j < 8; j++) o[j] = (short)sT[cg0 * 8 + j][dh];
        *(s16x8*)&dst[(size_t)dh * TSEQ + cg0 * 8] = o;
    }
}

// --------------------------- flash attention -------------------------------
// Block: 64 query rows for one (b,h). 4 waves x 16 rows. j-loop over 64-key
// tiles up to the causal diagonal. Online softmax in base-2 (Q pre-scaled).
__global__ __launch_bounds__(256) void attn_kernel(
    const unsigned short* __restrict__ Qb,   // [24][4096][64]
    const unsigned short* __restrict__ Kb,   // [24][4096][64]
    const unsigned short* __restrict__ Vt,   // [24][64][4096]
    unsigned short* __restrict__ Ob)         // [2][4096][768]
{
    __shared__ unsigned short sK[64][72];
    __shared__ unsigned short sV[64][72];
    __shared__ unsigned short sP[4][16][72];
    const int bh = blockIdx.y;
    const int q0 = blockIdx.x * 64;
    const int tid = threadIdx.x;
    const int w = tid >> 6, l = tid & 63, g = l >> 4, l15 = l & 15;
    const int row0 = tid >> 3, cg0 = tid & 7;

    const unsigned short* Qp = Qb + ((size_t)bh * TSEQ + q0 + w * 16 + l15) * DHEAD;
    s16x8 aq0 = *(const s16x8*)&Qp[g * 8];
    s16x8 aq1 = *(const s16x8*)&Qp[32 + g * 8];

    f32x4 oacc[4];
#pragma unroll
    for (int nt = 0; nt < 4; nt++) oacc[nt] = (f32x4){0.f, 0.f, 0.f, 0.f};
    float mrow[4], lrow[4];
#pragma unroll
    for (int r = 0; r < 4; r++) { mrow[r] = -1e30f; lrow[r] = 0.f; }

    const unsigned short* Kbase = Kb + (size_t)bh * TSEQ * DHEAD;
    const unsigned short* Vbase = Vt + (size_t)bh * DHEAD * TSEQ;
    const int ntile = blockIdx.x + 1;

    for (int jt = 0; jt < ntile; jt++) {
        const int kt = jt * 64;
        *(s16x8*)&sK[row0][cg0 * 8]      = *(const s16x8*)&Kbase[(size_t)(kt + row0) * DHEAD + cg0 * 8];
        *(s16x8*)&sK[row0 + 32][cg0 * 8] = *(const s16x8*)&Kbase[(size_t)(kt + row0 + 32) * DHEAD + cg0 * 8];
        *(s16x8*)&sV[row0][cg0 * 8]      = *(const s16x8*)&Vbase[(size_t)row0 * TSEQ + kt + cg0 * 8];
        *(s16x8*)&sV[row0 + 32][cg0 * 8] = *(const s16x8*)&Vbase[(size_t)(row0 + 32) * TSEQ + kt + cg0 * 8];
        __syncthreads();

        // S = Q K^T  (16x64 per wave)
        f32x4 sf[4];
#pragma unroll
        for (int nt = 0; nt < 4; nt++) sf[nt] = (f32x4){0.f, 0.f, 0.f, 0.f};
#pragma unroll
        for (int ks = 0; ks < 2; ks++) {
            s16x8 aq = ks ? aq1 : aq0;
#pragma unroll
            for (int nt = 0; nt < 4; nt++) {
                s16x8 bk = *(const s16x8*)&sK[nt * 16 + l15][ks * 32 + g * 8];
                sf[nt] = __builtin_amdgcn_mfma_f32_16x16x32_bf16(aq, bk, sf[nt], 0, 0, 0);
            }
        }

        // causal mask on the diagonal tile
        if (jt == ntile - 1) {
#pragma unroll
            for (int nt = 0; nt < 4; nt++)
#pragma unroll
                for (int r = 0; r < 4; r++)
                    if (nt * 16 + l15 > w * 16 + g * 4 + r) sf[nt][r] = -1e30f;
        }

        const float C2 = 1.44269504f;  // log2(e)
        float nm[4];
#pragma unroll
        for (int r = 0; r < 4; r++) {
            sf[0][r] *= C2; sf[1][r] *= C2; sf[2][r] *= C2; sf[3][r] *= C2;
            nm[r] = fmaxf(fmaxf(sf[0][r], sf[1][r]), fmaxf(sf[2][r], sf[3][r]));
        }
#pragma unroll
        for (int d = 1; d < 16; d <<= 1)
#pragma unroll
            for (int r = 0; r < 4; r++)
                nm[r] = fmaxf(nm[r], __shfl_xor(nm[r], d, 64));

        float alpha[4], rs[4];
#pragma unroll
        for (int r = 0; r < 4; r++) {
            nm[r] = fmaxf(mrow[r], nm[r]);
            alpha[r] = exp2f(mrow[r] - nm[r]);
            mrow[r] = nm[r];
            rs[r] = 0.f;
        }
#pragma unroll
        for (int nt = 0; nt < 4; nt++)
#pragma unroll
            for (int r = 0; r < 4; r++) {
                float p = exp2f(sf[nt][r] - nm[r]);
                sf[nt][r] = p;
                rs[r] += p;
            }
#pragma unroll
        for (int d = 1; d < 16; d <<= 1)
#pragma unroll
            for (int r = 0; r < 4; r++)
                rs[r] += __shfl_xor(rs[r], d, 64);
#pragma unroll
        for (int r = 0; r < 4; r++) lrow[r] = lrow[r] * alpha[r] + rs[r];
#pragma unroll
        for (int nt = 0; nt < 4; nt++)
#pragma unroll
            for (int r = 0; r < 4; r++) oacc[nt][r] *= alpha[r];

        // P: C-layout -> A-layout via per-wave LDS slice (bf16)
#pragma unroll
        for (int nt = 0; nt < 4; nt++)
#pragma unroll
            for (int r = 0; r < 4; r++)
                sP[w][g * 4 + r][nt * 16 + l15] = f2bf(sf[nt][r]);

        // O += P V
#pragma unroll
        for (int ks = 0; ks < 2; ks++) {
            s16x8 ap = *(const s16x8*)&sP[w][l15][ks * 32 + g * 8];
#pragma unroll
            for (int nt = 0; nt < 4; nt++) {
                s16x8 bv = *(const s16x8*)&sV[nt * 16 + l15][ks * 32 + g * 8];
                oacc[nt] = __builtin_amdgcn_mfma_f32_16x16x32_bf16(ap, bv, oacc[nt], 0, 0, 0);
            }
        }
        __syncthreads();
    }

    const int b = bh / NHEADS, h = bh - b * NHEADS;
    float inv[4];
#pragma unroll
    for (int r = 0; r < 4; r++) inv[r] = 1.0f / lrow[r];
#pragma unroll
    for (int nt = 0; nt < 4; nt++)
#pragma unroll
        for (int r = 0; r < 4; r++) {
            int rowg = q0 + w * 16 + g * 4 + r;
            Ob[((size_t)b * TSEQ + rowg) * CMODEL + h * DHEAD + nt * 16 + l15] =
                f2bf(oacc[nt][r] * inv[r]);
        }
}

// --------------------------- output projection GEMM ------------------------
__global__ __launch_bounds__(256) void gemm_out_kernel(
    const unsigned short* __restrict__ A,    // Ob [8192][768] bf16
    const unsigned short* __restrict__ Bw,   // woutb [768][768] bf16
    const float* __restrict__ bias,          // [768]
    float* __restrict__ out)                 // [8192][768] fp32
{
    __shared__ unsigned short sA[64][72];
    __shared__ unsigned short sB[64][72];
    const int n0 = blockIdx.x * 64;
    const int m0 = blockIdx.y * 64;
    const int tid = threadIdx.x;
    const int w = tid >> 6, l = tid & 63, g = l >> 4, l15 = l & 15;
    const int row0 = tid >> 3, cg0 = tid & 7;

    f32x4 acc[4];
#pragma unroll
    for (int nt = 0; nt < 4; nt++) acc[nt] = (f32x4){0.f, 0.f, 0.f, 0.f};

    for (int k0 = 0; k0 < 768; k0 += 64) {
        *(s16x8*)&sA[row0][cg0 * 8]      = *(const s16x8*)&A[(m0 + row0) * 768 + k0 + cg0 * 8];
        *(s16x8*)&sA[row0 + 32][cg0 * 8] = *(const s16x8*)&A[(m0 + row0 + 32) * 768 + k0 + cg0 * 8];
        *(s16x8*)&sB[row0][cg0 * 8]      = *(const s16x8*)&Bw[(n0 + row0) * 768 + k0 + cg0 * 8];
        *(s16x8*)&sB[row0 + 32][cg0 * 8] = *(const s16x8*)&Bw[(n0 + row0 + 32) * 768 + k0 + cg0 * 8];
        __syncthreads();
#pragma unroll
        for (int ks = 0; ks < 2; ks++) {
            s16x8 af = *(const s16x8*)&sA[w * 16 + l15][ks * 32 + g * 8];
#pragma unroll
            for (int nt = 0; nt < 4; nt++) {
                s16x8 bf = *(const s16x8*)&sB[nt * 16 + l15][ks * 32 + g * 8];
                acc[nt] = __builtin_amdgcn_mfma_f32_16x16x32_bf16(af, bf, acc[nt], 0, 0, 0);
            }
        }
        __syncthreads();
    }

#pragma unroll
    for (int nt = 0; nt < 4; nt++) {
        int n = n0 + nt * 16 + l15;
        float bv = bias[n];
#pragma unroll
        for (int r = 0; r < 4; r++) {
            int m = m0 + w * 16 + g * 4 + r;
            out[(size_t)m * CMODEL + n] = acc[nt][r] + bv;
        }
    }
}

// --------------------------- launch ----------------------------------------
extern "C" void kernel_launch(void* const* d_in, const int* in_sizes, int n_in,
                              void* d_out, int out_size, void* d_ws, size_t ws_size,
                              hipStream_t stream) {
    const float* x     = (const float*)d_in[0];
    const float* w_qkv = (const float*)d_in[1];
    const float* b_qkv = (const float*)d_in[2];
    const float* w_out = (const float*)d_in[3];
    const float* b_out = (const float*)d_in[4];
    float* out = (float*)d_out;

    char* ws = (char*)d_ws;
    size_t off = 0;
    auto alloc = [&](size_t bytes) -> unsigned short* {
        unsigned short* p = (unsigned short*)(ws + off);
        off += (bytes + 255) & ~(size_t)255;
        return p;
    };
    unsigned short* xb    = alloc((size_t)MTOT * CMODEL * 2);
    unsigned short* wqkvb = alloc((size_t)NQKV * CMODEL * 2);
    unsigned short* woutb = alloc((size_t)CMODEL * CMODEL * 2);
    unsigned short* Qb    = alloc((size_t)BATCH * NHEADS * TSEQ * DHEAD * 2);
    unsigned short* Kb    = alloc((size_t)BATCH * NHEADS * TSEQ * DHEAD * 2);
    unsigned short* Vb    = alloc((size_t)BATCH * NHEADS * TSEQ * DHEAD * 2);
    unsigned short* Vt    = alloc((size_t)BATCH * NHEADS * TSEQ * DHEAD * 2);
    unsigned short* Ob    = alloc((size_t)MTOT * CMODEL * 2);

    int n4x = MTOT * CMODEL / 4;
    cvt_bf16_kernel<<<dim3((n4x + 255) / 256), 256, 0, stream>>>(x, xb, n4x);
    int n4q = NQKV * CMODEL / 4;
    cvt_bf16_kernel<<<dim3((n4q + 255) / 256), 256, 0, stream>>>(w_qkv, wqkvb, n4q);
    int n4o = CMODEL * CMODEL / 4;
    cvt_bf16_kernel<<<dim3((n4o + 255) / 256), 256, 0, stream>>>(w_out, woutb, n4o);

    gemm_qkv_kernel<<<dim3(NQKV / 64, MTOT / 64), 256, 0, stream>>>(
        xb, wqkvb, b_qkv, Qb, Kb, Vb);
    transpose_v_kernel<<<dim3(TSEQ / 64, BATCH * NHEADS), 256, 0, stream>>>(Vb, Vt);
    attn_kernel<<<dim3(TSEQ / 64, BATCH * NHEADS), 256, 0, stream>>>(Qb, Kb, Vt, Ob);
    gemm_out_kernel<<<dim3(CMODEL / 64, MTOT / 64), 256, 0, stream>>>(Ob, woutb, b_out, out);
}

// Round 2
// 365.068 us; speedup vs baseline: 1.3456x; 1.3456x over previous
//
#include <hip/hip_runtime.h>

// ---------------------------------------------------------------------------
// MultiHeadCausalAttention: B=2, T=4096, C=768, H=12, Dh=64
// bf16 MFMA pipeline: cvt -> QKV GEMM -> V transpose -> flash attn -> out GEMM
// Attn v2: S^T formulation (per-lane scalar softmax state), paired causal
// tiles for load balance, register-hoisted K/V fragments.
// ---------------------------------------------------------------------------

#define NHEADS 12
#define DHEAD  64
#define TSEQ   4096
#define BATCH  2
#define CMODEL 768
#define MTOT   (BATCH * TSEQ)   /* 8192 */
#define NQKV   (3 * CMODEL)     /* 2304 */

typedef __attribute__((ext_vector_type(8))) short s16x8;
typedef __attribute__((ext_vector_type(4))) float f32x4;
typedef __attribute__((ext_vector_type(4))) unsigned short u16x4;

__device__ __forceinline__ unsigned short f2bf(float f) {
    unsigned u = __builtin_bit_cast(unsigned, f);
    u += 0x7fffu + ((u >> 16) & 1u);   // round-to-nearest-even
    return (unsigned short)(u >> 16);
}

__device__ __forceinline__ float fexp2(float x) {
    return __builtin_amdgcn_exp2f(x);
}

// --------------------------- fp32 -> bf16 cvt ------------------------------
__global__ __launch_bounds__(256) void cvt_bf16_kernel(
    const float* __restrict__ src, unsigned short* __restrict__ dst, int n4)
{
    int i = blockIdx.x * 256 + threadIdx.x;
    if (i < n4) {
        f32x4 v = ((const f32x4*)src)[i];
        u16x4 o;
        o.x = f2bf(v.x); o.y = f2bf(v.y); o.z = f2bf(v.z); o.w = f2bf(v.w);
        ((u16x4*)dst)[i] = o;
    }
}

// --------------------------- QKV projection GEMM ---------------------------
// C[m,n] = sum_k A[m,k] * Bw[n,k] + bias[n]; scatter to Q/K/V [B,H,T,Dh] bf16.
// Q gets pre-scaled by 1/sqrt(Dh) * log2(e) (softmax runs in base 2).
__global__ __launch_bounds__(256) void gemm_qkv_kernel(
    const unsigned short* __restrict__ A,    // [8192][768] bf16 (x)
    const unsigned short* __restrict__ Bw,   // [2304][768] bf16 (w_qkv)
    const float* __restrict__ bias,          // [2304]
    unsigned short* __restrict__ Qb,
    unsigned short* __restrict__ Kb,
    unsigned short* __restrict__ Vb)
{
    __shared__ unsigned short sA[64][72];
    __shared__ unsigned short sB[64][72];
    const int n0 = blockIdx.x * 64;
    const int m0 = blockIdx.y * 64;
    const int tid = threadIdx.x;
    const int w = tid >> 6, l = tid & 63, g = l >> 4, l15 = l & 15;
    const int row0 = tid >> 3, cg0 = tid & 7;

    f32x4 acc[4];
#pragma unroll
    for (int nt = 0; nt < 4; nt++) acc[nt] = (f32x4){0.f, 0.f, 0.f, 0.f};

    for (int k0 = 0; k0 < 768; k0 += 64) {
        *(s16x8*)&sA[row0][cg0 * 8]      = *(const s16x8*)&A[(m0 + row0) * 768 + k0 + cg0 * 8];
        *(s16x8*)&sA[row0 + 32][cg0 * 8] = *(const s16x8*)&A[(m0 + row0 + 32) * 768 + k0 + cg0 * 8];
        *(s16x8*)&sB[row0][cg0 * 8]      = *(const s16x8*)&Bw[(n0 + row0) * 768 + k0 + cg0 * 8];
        *(s16x8*)&sB[row0 + 32][cg0 * 8] = *(const s16x8*)&Bw[(n0 + row0 + 32) * 768 + k0 + cg0 * 8];
        __syncthreads();
#pragma unroll
        for (int ks = 0; ks < 2; ks++) {
            s16x8 af = *(const s16x8*)&sA[w * 16 + l15][ks * 32 + g * 8];
#pragma unroll
            for (int nt = 0; nt < 4; nt++) {
                s16x8 bf = *(const s16x8*)&sB[nt * 16 + l15][ks * 32 + g * 8];
                acc[nt] = __builtin_amdgcn_mfma_f32_16x16x32_bf16(af, bf, acc[nt], 0, 0, 0);
            }
        }
        __syncthreads();
    }

#pragma unroll
    for (int nt = 0; nt < 4; nt++) {
        int n = n0 + nt * 16 + l15;
        float bv = bias[n];
        int three = n / 768;
        int hh = (n - three * 768) >> 6;
        int dh = n & 63;
        unsigned short* dst = (three == 0) ? Qb : ((three == 1) ? Kb : Vb);
        // 0.125 * log2(e): attention softmax runs in base-2
        float scale = (three == 0) ? 0.18033688011f : 1.0f;
#pragma unroll
        for (int r = 0; r < 4; r++) {
            int m = m0 + w * 16 + g * 4 + r;
            int b = m >> 12, t = m & 4095;
            float v = (acc[nt][r] + bv) * scale;
            dst[(((b * NHEADS + hh) * TSEQ + t) * DHEAD) + dh] = f2bf(v);
        }
    }
}

// --------------------------- V transpose -----------------------------------
// Vb [bh][t][dh] -> Vt [bh][dh][t]
__global__ __launch_bounds__(256) void transpose_v_kernel(
    const unsigned short* __restrict__ Vb, unsigned short* __restrict__ Vt)
{
    __shared__ unsigned short sT[64][72];
    const int bh = blockIdx.y;
    const int t0 = blockIdx.x * 64;
    const int tid = threadIdx.x;
    const int row0 = tid >> 3, cg0 = tid & 7;

    const unsigned short* src = Vb + ((size_t)bh * TSEQ + t0) * DHEAD;
    *(s16x8*)&sT[row0][cg0 * 8]      = *(const s16x8*)&src[row0 * DHEAD + cg0 * 8];
    *(s16x8*)&sT[row0 + 32][cg0 * 8] = *(const s16x8*)&src[(row0 + 32) * DHEAD + cg0 * 8];
    __syncthreads();

    unsigned short* dst = Vt + (size_t)bh * DHEAD * TSEQ + t0;
#pragma unroll
    for (int p = 0; p < 2; p++) {
        int dh = row0 + p * 32;
        s16x8 o;
#pragma unroll
        for (int j = 0; j < 8; j++) o[j] = (short)sT[cg0 * 8 + j][dh];
        *(s16x8*)&dst[(size_t)dh * TSEQ + cg0 * 8] = o;
    }
}

// --------------------------- flash attention v2 ----------------------------
// S^T = K Q^T so each lane owns ONE query column: softmax state is scalar.
// Block pairs query tiles i and 63-i => constant 65 strip-iterations.
// K/V fragments hoisted to registers once per key tile, reused by both strips.

__device__ __forceinline__ void attn_strip(
    const s16x8 ak[2][4], const s16x8 av[2][4],
    s16x8 qf0, s16x8 qf1,
    unsigned short (* __restrict__ sPTw)[72],
    f32x4* __restrict__ o, float& m, float& l,
    int kt, int qg, bool mask, int g, int l15)
{
    // S^T tile: rows = 64 keys (nt,g,r), cols = 16 queries (l15)
    f32x4 st[4];
#pragma unroll
    for (int nt = 0; nt < 4; nt++) st[nt] = (f32x4){0.f, 0.f, 0.f, 0.f};
#pragma unroll
    for (int nt = 0; nt < 4; nt++)
        st[nt] = __builtin_amdgcn_mfma_f32_16x16x32_bf16(ak[0][nt], qf0, st[nt], 0, 0, 0);
#pragma unroll
    for (int nt = 0; nt < 4; nt++)
        st[nt] = __builtin_amdgcn_mfma_f32_16x16x32_bf16(ak[1][nt], qf1, st[nt], 0, 0, 0);

    if (mask) {
#pragma unroll
        for (int nt = 0; nt < 4; nt++)
#pragma unroll
            for (int r = 0; r < 4; r++)
                if (kt + nt * 16 + g * 4 + r > qg) st[nt][r] = -1e30f;
    }

    // max over 64 keys: 15 in-lane + butterfly over g (lanes l^16, l^32)
    float tm = st[0][0];
#pragma unroll
    for (int nt = 0; nt < 4; nt++)
#pragma unroll
        for (int r = 0; r < 4; r++) tm = fmaxf(tm, st[nt][r]);
    tm = fmaxf(tm, __shfl_xor(tm, 16, 64));
    tm = fmaxf(tm, __shfl_xor(tm, 32, 64));

    float nm = fmaxf(m, tm);
    float al = fexp2(m - nm);
    m = nm;

    float rs = 0.f;
#pragma unroll
    for (int nt = 0; nt < 4; nt++) {
        u16x4 pk;
#pragma unroll
        for (int r = 0; r < 4; r++) {
            float p = fexp2(st[nt][r] - nm);
            rs += p;
            pk[r] = f2bf(p);
        }
        // P row-major [q=l15][key]: 4 contiguous keys -> one b64 write
        *(u16x4*)&sPTw[l15][nt * 16 + g * 4] = pk;
    }
    rs += __shfl_xor(rs, 16, 64);
    rs += __shfl_xor(rs, 32, 64);
    l = l * al + rs;

#pragma unroll
    for (int nt = 0; nt < 4; nt++) {
        o[nt][0] *= al; o[nt][1] *= al; o[nt][2] *= al; o[nt][3] *= al;
    }

    // O^T += V^T P^T : B-operand = P rows (per-lane q = l15)
#pragma unroll
    for (int ks = 0; ks < 2; ks++) {
        s16x8 bp = *(const s16x8*)&sPTw[l15][ks * 32 + g * 8];
#pragma unroll
        for (int nt = 0; nt < 4; nt++)
            o[nt] = __builtin_amdgcn_mfma_f32_16x16x32_bf16(av[ks][nt], bp, o[nt], 0, 0, 0);
    }
}

__global__ __launch_bounds__(256) void attn_kernel(
    const unsigned short* __restrict__ Qb,   // [24][4096][64] (pre-scaled)
    const unsigned short* __restrict__ Kb,   // [24][4096][64]
    const unsigned short* __restrict__ Vt,   // [24][64][4096]
    unsigned short* __restrict__ Ob)         // [2][4096][768]
{
    __shared__ unsigned short sK[64][72];
    __shared__ unsigned short sV[64][72];
    __shared__ unsigned short sPT[4][16][72];
    const int bh = blockIdx.y;
    const int i  = blockIdx.x;               // 0..31
    const int q0a = i * 64;
    const int q0b = (63 - i) * 64;
    const int na = i + 1;                    // key tiles for strip A
    const int nb = 64 - i;                   // key tiles for strip B
    const int tid = threadIdx.x;
    const int w = tid >> 6, l = tid & 63, g = l >> 4, l15 = l & 15;
    const int row0 = tid >> 3, cg0 = tid & 7;

    // Q fragments (B-operand): lane holds Q[q = l15][k = ks*32 + g*8 + j]
    const unsigned short* Qpa = Qb + ((size_t)bh * TSEQ + q0a + w * 16 + l15) * DHEAD;
    const unsigned short* Qpb = Qb + ((size_t)bh * TSEQ + q0b + w * 16 + l15) * DHEAD;
    s16x8 qa0 = *(const s16x8*)&Qpa[g * 8];
    s16x8 qa1 = *(const s16x8*)&Qpa[32 + g * 8];
    s16x8 qb0 = *(const s16x8*)&Qpb[g * 8];
    s16x8 qb1 = *(const s16x8*)&Qpb[32 + g * 8];

    f32x4 oA[4], oB[4];
#pragma unroll
    for (int nt = 0; nt < 4; nt++) {
        oA[nt] = (f32x4){0.f, 0.f, 0.f, 0.f};
        oB[nt] = (f32x4){0.f, 0.f, 0.f, 0.f};
    }
    float mA = -1e30f, lA = 0.f, mB = -1e30f, lB = 0.f;
    const int qga = q0a + w * 16 + l15;
    const int qgb = q0b + w * 16 + l15;

    const unsigned short* Kbase = Kb + (size_t)bh * TSEQ * DHEAD;
    const unsigned short* Vbase = Vt + (size_t)bh * DHEAD * TSEQ;

    for (int jt = 0; jt < nb; jt++) {
        const int kt = jt * 64;
        *(s16x8*)&sK[row0][cg0 * 8]      = *(const s16x8*)&Kbase[(size_t)(kt + row0) * DHEAD + cg0 * 8];
        *(s16x8*)&sK[row0 + 32][cg0 * 8] = *(const s16x8*)&Kbase[(size_t)(kt + row0 + 32) * DHEAD + cg0 * 8];
        *(s16x8*)&sV[row0][cg0 * 8]      = *(const s16x8*)&Vbase[(size_t)row0 * TSEQ + kt + cg0 * 8];
        *(s16x8*)&sV[row0 + 32][cg0 * 8] = *(const s16x8*)&Vbase[(size_t)(row0 + 32) * TSEQ + kt + cg0 * 8];
        __syncthreads();

        // hoist K (A-op, rows=keys) and V^T (A-op, rows=d) fragments
        s16x8 ak[2][4], av[2][4];
#pragma unroll
        for (int ks = 0; ks < 2; ks++)
#pragma unroll
            for (int nt = 0; nt < 4; nt++) {
                ak[ks][nt] = *(const s16x8*)&sK[nt * 16 + l15][ks * 32 + g * 8];
                av[ks][nt] = *(const s16x8*)&sV[nt * 16 + l15][ks * 32 + g * 8];
            }

        if (jt < na)
            attn_strip(ak, av, qa0, qa1, sPT[w], oA, mA, lA, kt, qga, jt == na - 1, g, l15);
        attn_strip(ak, av, qb0, qb1, sPT[w], oB, mB, lB, kt, qgb, jt == nb - 1, g, l15);
        __syncthreads();
    }

    const int b = bh / NHEADS, h = bh - b * NHEADS;
    {
        float inv = 1.0f / lA;
#pragma unroll
        for (int nt = 0; nt < 4; nt++) {
            u16x4 pk;
#pragma unroll
            for (int r = 0; r < 4; r++) pk[r] = f2bf(oA[nt][r] * inv);
            *(u16x4*)&Ob[((size_t)b * TSEQ + qga) * CMODEL + h * DHEAD + nt * 16 + g * 4] = pk;
        }
    }
    {
        float inv = 1.0f / lB;
#pragma unroll
        for (int nt = 0; nt < 4; nt++) {
            u16x4 pk;
#pragma unroll
            for (int r = 0; r < 4; r++) pk[r] = f2bf(oB[nt][r] * inv);
            *(u16x4*)&Ob[((size_t)b * TSEQ + qgb) * CMODEL + h * DHEAD + nt * 16 + g * 4] = pk;
        }
    }
}

// --------------------------- output projection GEMM ------------------------
__global__ __launch_bounds__(256) void gemm_out_kernel(
    const unsigned short* __restrict__ A,    // Ob [8192][768] bf16
    const unsigned short* __restrict__ Bw,   // woutb [768][768] bf16
    const float* __restrict__ bias,          // [768]
    float* __restrict__ out)                 // [8192][768] fp32
{
    __shared__ unsigned short sA[64][72];
    __shared__ unsigned short sB[64][72];
    const int n0 = blockIdx.x * 64;
    const int m0 = blockIdx.y * 64;
    const int tid = threadIdx.x;
    const int w = tid >> 6, l = tid & 63, g = l >> 4, l15 = l & 15;
    const int row0 = tid >> 3, cg0 = tid & 7;

    f32x4 acc[4];
#pragma unroll
    for (int nt = 0; nt < 4; nt++) acc[nt] = (f32x4){0.f, 0.f, 0.f, 0.f};

    for (int k0 = 0; k0 < 768; k0 += 64) {
        *(s16x8*)&sA[row0][cg0 * 8]      = *(const s16x8*)&A[(m0 + row0) * 768 + k0 + cg0 * 8];
        *(s16x8*)&sA[row0 + 32][cg0 * 8] = *(const s16x8*)&A[(m0 + row0 + 32) * 768 + k0 + cg0 * 8];
        *(s16x8*)&sB[row0][cg0 * 8]      = *(const s16x8*)&Bw[(n0 + row0) * 768 + k0 + cg0 * 8];
        *(s16x8*)&sB[row0 + 32][cg0 * 8] = *(const s16x8*)&Bw[(n0 + row0 + 32) * 768 + k0 + cg0 * 8];
        __syncthreads();
#pragma unroll
        for (int ks = 0; ks < 2; ks++) {
            s16x8 af = *(const s16x8*)&sA[w * 16 + l15][ks * 32 + g * 8];
#pragma unroll
            for (int nt = 0; nt < 4; nt++) {
                s16x8 bf = *(const s16x8*)&sB[nt * 16 + l15][ks * 32 + g * 8];
                acc[nt] = __builtin_amdgcn_mfma_f32_16x16x32_bf16(af, bf, acc[nt], 0, 0, 0);
            }
        }
        __syncthreads();
    }

#pragma unroll
    for (int nt = 0; nt < 4; nt++) {
        int n = n0 + nt * 16 + l15;
        float bv = bias[n];
#pragma unroll
        for (int r = 0; r < 4; r++) {
            int m = m0 + w * 16 + g * 4 + r;
            out[(size_t)m * CMODEL + n] = acc[nt][r] + bv;
        }
    }
}

// --------------------------- launch ----------------------------------------
extern "C" void kernel_launch(void* const* d_in, const int* in_sizes, int n_in,
                              void* d_out, int out_size, void* d_ws, size_t ws_size,
                              hipStream_t stream) {
    const float* x     = (const float*)d_in[0];
    const float* w_qkv = (const float*)d_in[1];
    const float* b_qkv = (const float*)d_in[2];
    const float* w_out = (const float*)d_in[3];
    const float* b_out = (const float*)d_in[4];
    float* out = (float*)d_out;

    char* ws = (char*)d_ws;
    size_t off = 0;
    auto alloc = [&](size_t bytes) -> unsigned short* {
        unsigned short* p = (unsigned short*)(ws + off);
        off += (bytes + 255) & ~(size_t)255;
        return p;
    };
    unsigned short* xb    = alloc((size_t)MTOT * CMODEL * 2);
    unsigned short* wqkvb = alloc((size_t)NQKV * CMODEL * 2);
    unsigned short* woutb = alloc((size_t)CMODEL * CMODEL * 2);
    unsigned short* Qb    = alloc((size_t)BATCH * NHEADS * TSEQ * DHEAD * 2);
    unsigned short* Kb    = alloc((size_t)BATCH * NHEADS * TSEQ * DHEAD * 2);
    unsigned short* Vb    = alloc((size_t)BATCH * NHEADS * TSEQ * DHEAD * 2);
    unsigned short* Vt    = alloc((size_t)BATCH * NHEADS * TSEQ * DHEAD * 2);
    unsigned short* Ob    = alloc((size_t)MTOT * CMODEL * 2);

    int n4x = MTOT * CMODEL / 4;
    cvt_bf16_kernel<<<dim3((n4x + 255) / 256), 256, 0, stream>>>(x, xb, n4x);
    int n4q = NQKV * CMODEL / 4;
    cvt_bf16_kernel<<<dim3((n4q + 255) / 256), 256, 0, stream>>>(w_qkv, wqkvb, n4q);
    int n4o = CMODEL * CMODEL / 4;
    cvt_bf16_kernel<<<dim3((n4o + 255) / 256), 256, 0, stream>>>(w_out, woutb, n4o);

    gemm_qkv_kernel<<<dim3(NQKV / 64, MTOT / 64), 256, 0, stream>>>(
        xb, wqkvb, b_qkv, Qb, Kb, Vb);
    transpose_v_kernel<<<dim3(TSEQ / 64, BATCH * NHEADS), 256, 0, stream>>>(Vb, Vt);
    attn_kernel<<<dim3(32, BATCH * NHEADS), 256, 0, stream>>>(Qb, Kb, Vt, Ob);
    gemm_out_kernel<<<dim3(CMODEL / 64, MTOT / 64), 256, 0, stream>>>(Ob, woutb, b_out, out);
}

// Round 4
// 338.931 us; speedup vs baseline: 1.4493x; 1.0771x over previous
//
#include <hip/hip_runtime.h>

// ---------------------------------------------------------------------------
// MultiHeadCausalAttention: B=2, T=4096, C=768, H=12, Dh=64
// v3b: m97-style 128x128 GEMMs (global_load_lds + XOR-swizzled LDS),
//      V transposed in QKV epilogue, attn with 2 key tiles per barrier pair,
//      conflict-free swizzled LDS, packed bf16 converts (manual pack — the
//      __hip_bfloat162 bit_cast is not trivially copyable on this ROCm).
// ---------------------------------------------------------------------------

#define NHEADS 12
#define DHEAD  64
#define TSEQ   4096
#define BATCH  2
#define CMODEL 768
#define MTOT   (BATCH * TSEQ)   /* 8192 */
#define NQKV   (3 * CMODEL)     /* 2304 */

typedef __attribute__((ext_vector_type(8))) short s16x8;
typedef __attribute__((ext_vector_type(4))) float f32x4;
typedef __attribute__((ext_vector_type(4))) unsigned short u16x4;
typedef __attribute__((ext_vector_type(2))) unsigned int u32x2;

__device__ __forceinline__ unsigned short f2bf(float f) {
    unsigned u = __builtin_bit_cast(unsigned, f);
    u += 0x7fffu + ((u >> 16) & 1u);   // round-to-nearest-even
    return (unsigned short)(u >> 16);
}

__device__ __forceinline__ unsigned pk2bf(float a, float b) {
    return (unsigned)f2bf(a) | ((unsigned)f2bf(b) << 16);
}

__device__ __forceinline__ float fexp2(float x) {
    return __builtin_amdgcn_exp2f(x);
}

// async global -> LDS, 16B per lane. lds ptr must be the wave-uniform base;
// HW writes lane i at base + i*16.
__device__ __forceinline__ void async_load16(const void* g, void* l) {
    __builtin_amdgcn_global_load_lds(
        (const __attribute__((address_space(1))) unsigned*)g,
        (__attribute__((address_space(3))) unsigned*)l, 16, 0, 0);
}

// --------------------------- fp32 -> bf16 cvt ------------------------------
__global__ __launch_bounds__(256) void cvt_bf16_kernel(
    const float* __restrict__ src, unsigned short* __restrict__ dst, int n4)
{
    int i = blockIdx.x * 256 + threadIdx.x;
    if (i < n4) {
        f32x4 v = ((const f32x4*)src)[i];
        u16x4 o;
        o.x = f2bf(v.x); o.y = f2bf(v.y); o.z = f2bf(v.z); o.w = f2bf(v.w);
        ((u16x4*)dst)[i] = o;
    }
}

// --------------------------- QKV projection GEMM (128x128, m97-style) ------
// C[m,n] = sum_k A[m,k]*Bw[n,k] + bias[n]. Q scaled by 0.125*log2(e).
// Q,K scattered to [B,H,T,64]; V written TRANSPOSED to Vt [B,H,64,T].
__global__ __launch_bounds__(256) void gemm_qkv_kernel(
    const unsigned short* __restrict__ A,    // [8192][768] bf16
    const unsigned short* __restrict__ Bw,   // [2304][768] bf16
    const float* __restrict__ bias,          // [2304]
    unsigned short* __restrict__ Qb,
    unsigned short* __restrict__ Kb,
    unsigned short* __restrict__ Vt)
{
    __shared__ unsigned short sA[128][64];
    __shared__ unsigned short sB[128][64];
    const int n0 = blockIdx.x * 128;
    const int m0 = blockIdx.y * 128;
    const int tid = threadIdx.x;
    const int l = tid & 63, g = l >> 4, l15 = l & 15;
    const int w = tid >> 6, wm = w & 1, wn = w >> 1;
    const int wbase = tid & 192;             // w*64, wave-uniform

    f32x4 acc[4][4];
#pragma unroll
    for (int mt = 0; mt < 4; mt++)
#pragma unroll
        for (int nt = 0; nt < 4; nt++) acc[mt][nt] = (f32x4){0.f, 0.f, 0.f, 0.f};

    for (int k0 = 0; k0 < 768; k0 += 64) {
#pragma unroll
        for (int i = 0; i < 4; i++) {
            const int idx = i * 256 + tid;
            const int row = idx >> 3, pc = idx & 7;
            const int lc = pc ^ (row & 7);   // logical chunk (swizzled placement)
            async_load16(&A[(size_t)(m0 + row) * 768 + k0 + lc * 8],
                         &sA[0][0] + (size_t)(i * 256 + wbase) * 8);
            async_load16(&Bw[(size_t)(n0 + row) * 768 + k0 + lc * 8],
                         &sB[0][0] + (size_t)(i * 256 + wbase) * 8);
        }
        __syncthreads();
#pragma unroll
        for (int ks = 0; ks < 2; ks++) {
            const int cc = ((ks * 4 + g) ^ (l15 & 7)) * 8;
            s16x8 af[4], bf[4];
#pragma unroll
            for (int mt = 0; mt < 4; mt++)
                af[mt] = *(const s16x8*)&sA[wm * 64 + mt * 16 + l15][cc];
#pragma unroll
            for (int nt = 0; nt < 4; nt++)
                bf[nt] = *(const s16x8*)&sB[wn * 64 + nt * 16 + l15][cc];
#pragma unroll
            for (int mt = 0; mt < 4; mt++)
#pragma unroll
                for (int nt = 0; nt < 4; nt++)
                    acc[mt][nt] = __builtin_amdgcn_mfma_f32_16x16x32_bf16(
                        af[mt], bf[nt], acc[mt][nt], 0, 0, 0);
        }
        __syncthreads();
    }

    const int seg = n0 / 768;                // 0=Q 1=K 2=V (uniform per block)
    if (seg < 2) {
        unsigned short* dst = (seg == 0) ? Qb : Kb;
        const float sc = (seg == 0) ? 0.18033688011f : 1.0f;  // 0.125*log2e
#pragma unroll
        for (int nt = 0; nt < 4; nt++) {
            const int n = n0 + wn * 64 + nt * 16 + l15;
            const float bv = bias[n];
            const int hh = (n - seg * 768) >> 6;
            const int dh = n & 63;
#pragma unroll
            for (int mt = 0; mt < 4; mt++)
#pragma unroll
                for (int r = 0; r < 4; r++) {
                    const int m = m0 + wm * 64 + mt * 16 + g * 4 + r;
                    const int b = m >> 12, t = m & 4095;
                    dst[(((size_t)(b * NHEADS + hh) * TSEQ + t) << 6) + dh] =
                        f2bf((acc[mt][nt][r] + bv) * sc);
                }
        }
    } else {
#pragma unroll
        for (int nt = 0; nt < 4; nt++) {
            const int n = n0 + wn * 64 + nt * 16 + l15;
            const float bv = bias[n];
            const int hh = (n - 1536) >> 6;
            const int dh = n & 63;
#pragma unroll
            for (int mt = 0; mt < 4; mt++) {
                const int mg = m0 + wm * 64 + mt * 16 + g * 4;
                const int b = mg >> 12, t = mg & 4095;
                u16x4 pk;
#pragma unroll
                for (int r = 0; r < 4; r++) pk[r] = f2bf(acc[mt][nt][r] + bv);
                *(u16x4*)&Vt[((size_t)(b * NHEADS + hh) * DHEAD + dh) * TSEQ + t] = pk;
            }
        }
    }
}

// --------------------------- flash attention v3 ----------------------------
// S^T = K Q^T (per-lane scalar softmax state), paired causal tiles,
// 2 key tiles per barrier pair, XOR-swizzled conflict-free LDS.

__device__ __forceinline__ void attn_strip(
    const s16x8 ak[2][4], const s16x8 av[2][4],
    s16x8 qf0, s16x8 qf1,
    unsigned short (* __restrict__ sPTw)[64],
    f32x4* __restrict__ o, float& m, float& l,
    int kt, int qg, bool mask, int g, int l15)
{
    f32x4 st[4];
#pragma unroll
    for (int nt = 0; nt < 4; nt++) st[nt] = (f32x4){0.f, 0.f, 0.f, 0.f};
#pragma unroll
    for (int nt = 0; nt < 4; nt++)
        st[nt] = __builtin_amdgcn_mfma_f32_16x16x32_bf16(ak[0][nt], qf0, st[nt], 0, 0, 0);
#pragma unroll
    for (int nt = 0; nt < 4; nt++)
        st[nt] = __builtin_amdgcn_mfma_f32_16x16x32_bf16(ak[1][nt], qf1, st[nt], 0, 0, 0);

    if (mask) {
#pragma unroll
        for (int nt = 0; nt < 4; nt++)
#pragma unroll
            for (int r = 0; r < 4; r++)
                if (kt + nt * 16 + g * 4 + r > qg) st[nt][r] = -1e30f;
    }

    float tm = st[0][0];
#pragma unroll
    for (int nt = 0; nt < 4; nt++)
#pragma unroll
        for (int r = 0; r < 4; r++) tm = fmaxf(tm, st[nt][r]);
    tm = fmaxf(tm, __shfl_xor(tm, 16, 64));
    tm = fmaxf(tm, __shfl_xor(tm, 32, 64));

    const float nm = fmaxf(m, tm);
    const float al = fexp2(m - nm);
    m = nm;

    float rs = 0.f;
    const int xk = l15 & 7;
#pragma unroll
    for (int nt = 0; nt < 4; nt++) {
        float p0 = fexp2(st[nt][0] - nm);
        float p1 = fexp2(st[nt][1] - nm);
        float p2 = fexp2(st[nt][2] - nm);
        float p3 = fexp2(st[nt][3] - nm);
        rs += (p0 + p1) + (p2 + p3);
        u32x2 pk;
        pk.x = pk2bf(p0, p1);
        pk.y = pk2bf(p2, p3);
        const int phys = ((nt * 2 + (g >> 1)) ^ xk) * 8 + (g & 1) * 4;
        *(u32x2*)&sPTw[l15][phys] = pk;
    }
    rs += __shfl_xor(rs, 16, 64);
    rs += __shfl_xor(rs, 32, 64);
    l = l * al + rs;

#pragma unroll
    for (int nt = 0; nt < 4; nt++) {
        o[nt][0] *= al; o[nt][1] *= al; o[nt][2] *= al; o[nt][3] *= al;
    }

#pragma unroll
    for (int ks = 0; ks < 2; ks++) {
        s16x8 bp = *(const s16x8*)&sPTw[l15][((ks * 4 + g) ^ xk) * 8];
#pragma unroll
        for (int nt = 0; nt < 4; nt++)
            o[nt] = __builtin_amdgcn_mfma_f32_16x16x32_bf16(av[ks][nt], bp, o[nt], 0, 0, 0);
    }
}

__global__ __launch_bounds__(256) void attn_kernel(
    const unsigned short* __restrict__ Qb,   // [24][4096][64] (pre-scaled)
    const unsigned short* __restrict__ Kb,   // [24][4096][64]
    const unsigned short* __restrict__ Vt,   // [24][64][4096]
    unsigned short* __restrict__ Ob)         // [2][4096][768]
{
    __shared__ unsigned short sK[2][64][64];
    __shared__ unsigned short sV[2][64][64];
    __shared__ unsigned short sPT[4][16][64];
    const int bh = blockIdx.y;
    const int i  = blockIdx.x;               // 0..31
    const int q0a = i * 64;
    const int q0b = (63 - i) * 64;
    const int na = i + 1;
    const int nb = 64 - i;
    const int tid = threadIdx.x;
    const int w = tid >> 6, l = tid & 63, g = l >> 4, l15 = l & 15;

    const unsigned short* Qpa = Qb + ((size_t)bh * TSEQ + q0a + w * 16 + l15) * DHEAD;
    const unsigned short* Qpb = Qb + ((size_t)bh * TSEQ + q0b + w * 16 + l15) * DHEAD;
    s16x8 qa0 = *(const s16x8*)&Qpa[g * 8];
    s16x8 qa1 = *(const s16x8*)&Qpa[32 + g * 8];
    s16x8 qb0 = *(const s16x8*)&Qpb[g * 8];
    s16x8 qb1 = *(const s16x8*)&Qpb[32 + g * 8];

    f32x4 oA[4], oB[4];
#pragma unroll
    for (int nt = 0; nt < 4; nt++) {
        oA[nt] = (f32x4){0.f, 0.f, 0.f, 0.f};
        oB[nt] = (f32x4){0.f, 0.f, 0.f, 0.f};
    }
    float mA = -1e30f, lA = 0.f, mB = -1e30f, lB = 0.f;
    const int qga = q0a + w * 16 + l15;
    const int qgb = q0b + w * 16 + l15;

    const unsigned short* Kbase = Kb + (size_t)bh * TSEQ * DHEAD;
    const unsigned short* Vbase = Vt + (size_t)bh * DHEAD * TSEQ;
    const int xk = l15 & 7;

    for (int jt0 = 0; jt0 < nb; jt0 += 2) {
        const int t2 = (jt0 + 1 < nb) ? 2 : 1;
#pragma unroll
        for (int u = 0; u < 2; u++) {
            if (u < t2) {
                const int kt = (jt0 + u) * 64;
#pragma unroll
                for (int p = 0; p < 2; p++) {
                    const int idx = p * 256 + tid;
                    const int row = idx >> 3, ch = idx & 7;
                    const int cs = (ch ^ (row & 7)) * 8;
                    *(s16x8*)&sK[u][row][cs] =
                        *(const s16x8*)&Kbase[(size_t)(kt + row) * DHEAD + ch * 8];
                    *(s16x8*)&sV[u][row][cs] =
                        *(const s16x8*)&Vbase[(size_t)row * TSEQ + kt + ch * 8];
                }
            }
        }
        __syncthreads();
        for (int u = 0; u < t2; u++) {
            const int jt = jt0 + u;
            const int kt = jt * 64;
            s16x8 ak[2][4], av[2][4];
#pragma unroll
            for (int ks = 0; ks < 2; ks++) {
                const int cc = ((ks * 4 + g) ^ xk) * 8;
#pragma unroll
                for (int nt = 0; nt < 4; nt++) {
                    ak[ks][nt] = *(const s16x8*)&sK[u][nt * 16 + l15][cc];
                    av[ks][nt] = *(const s16x8*)&sV[u][nt * 16 + l15][cc];
                }
            }
            if (jt < na)
                attn_strip(ak, av, qa0, qa1, sPT[w], oA, mA, lA, kt, qga, jt == na - 1, g, l15);
            attn_strip(ak, av, qb0, qb1, sPT[w], oB, mB, lB, kt, qgb, jt == nb - 1, g, l15);
        }
        __syncthreads();
    }

    const int b = bh / NHEADS, h = bh - b * NHEADS;
    {
        const float inv = 1.0f / lA;
#pragma unroll
        for (int nt = 0; nt < 4; nt++) {
            u32x2 pk;
            pk.x = pk2bf(oA[nt][0] * inv, oA[nt][1] * inv);
            pk.y = pk2bf(oA[nt][2] * inv, oA[nt][3] * inv);
            *(u32x2*)&Ob[((size_t)b * TSEQ + qga) * CMODEL + h * DHEAD + nt * 16 + g * 4] = pk;
        }
    }
    {
        const float inv = 1.0f / lB;
#pragma unroll
        for (int nt = 0; nt < 4; nt++) {
            u32x2 pk;
            pk.x = pk2bf(oB[nt][0] * inv, oB[nt][1] * inv);
            pk.y = pk2bf(oB[nt][2] * inv, oB[nt][3] * inv);
            *(u32x2*)&Ob[((size_t)b * TSEQ + qgb) * CMODEL + h * DHEAD + nt * 16 + g * 4] = pk;
        }
    }
}

// --------------------------- output projection GEMM (128x128) --------------
__global__ __launch_bounds__(256) void gemm_out_kernel(
    const unsigned short* __restrict__ A,    // Ob [8192][768] bf16
    const unsigned short* __restrict__ Bw,   // woutb [768][768] bf16
    const float* __restrict__ bias,          // [768]
    float* __restrict__ out)                 // [8192][768] fp32
{
    __shared__ unsigned short sA[128][64];
    __shared__ unsigned short sB[128][64];
    const int n0 = blockIdx.x * 128;
    const int m0 = blockIdx.y * 128;
    const int tid = threadIdx.x;
    const int l = tid & 63, g = l >> 4, l15 = l & 15;
    const int w = tid >> 6, wm = w & 1, wn = w >> 1;
    const int wbase = tid & 192;

    f32x4 acc[4][4];
#pragma unroll
    for (int mt = 0; mt < 4; mt++)
#pragma unroll
        for (int nt = 0; nt < 4; nt++) acc[mt][nt] = (f32x4){0.f, 0.f, 0.f, 0.f};

    for (int k0 = 0; k0 < 768; k0 += 64) {
#pragma unroll
        for (int i = 0; i < 4; i++) {
            const int idx = i * 256 + tid;
            const int row = idx >> 3, pc = idx & 7;
            const int lc = pc ^ (row & 7);
            async_load16(&A[(size_t)(m0 + row) * 768 + k0 + lc * 8],
                         &sA[0][0] + (size_t)(i * 256 + wbase) * 8);
            async_load16(&Bw[(size_t)(n0 + row) * 768 + k0 + lc * 8],
                         &sB[0][0] + (size_t)(i * 256 + wbase) * 8);
        }
        __syncthreads();
#pragma unroll
        for (int ks = 0; ks < 2; ks++) {
            const int cc = ((ks * 4 + g) ^ (l15 & 7)) * 8;
            s16x8 af[4], bf[4];
#pragma unroll
            for (int mt = 0; mt < 4; mt++)
                af[mt] = *(const s16x8*)&sA[wm * 64 + mt * 16 + l15][cc];
#pragma unroll
            for (int nt = 0; nt < 4; nt++)
                bf[nt] = *(const s16x8*)&sB[wn * 64 + nt * 16 + l15][cc];
#pragma unroll
            for (int mt = 0; mt < 4; mt++)
#pragma unroll
                for (int nt = 0; nt < 4; nt++)
                    acc[mt][nt] = __builtin_amdgcn_mfma_f32_16x16x32_bf16(
                        af[mt], bf[nt], acc[mt][nt], 0, 0, 0);
        }
        __syncthreads();
    }

#pragma unroll
    for (int nt = 0; nt < 4; nt++) {
        const int n = n0 + wn * 64 + nt * 16 + l15;
        const float bv = bias[n];
#pragma unroll
        for (int mt = 0; mt < 4; mt++)
#pragma unroll
            for (int r = 0; r < 4; r++) {
                const int m = m0 + wm * 64 + mt * 16 + g * 4 + r;
                out[(size_t)m * CMODEL + n] = acc[mt][nt][r] + bv;
            }
    }
}

// --------------------------- launch ----------------------------------------
extern "C" void kernel_launch(void* const* d_in, const int* in_sizes, int n_in,
                              void* d_out, int out_size, void* d_ws, size_t ws_size,
                              hipStream_t stream) {
    const float* x     = (const float*)d_in[0];
    const float* w_qkv = (const float*)d_in[1];
    const float* b_qkv = (const float*)d_in[2];
    const float* w_out = (const float*)d_in[3];
    const float* b_out = (const float*)d_in[4];
    float* out = (float*)d_out;

    char* ws = (char*)d_ws;
    size_t off = 0;
    auto alloc = [&](size_t bytes) -> unsigned short* {
        unsigned short* p = (unsigned short*)(ws + off);
        off += (bytes + 255) & ~(size_t)255;
        return p;
    };
    unsigned short* xb    = alloc((size_t)MTOT * CMODEL * 2);
    unsigned short* wqkvb = alloc((size_t)NQKV * CMODEL * 2);
    unsigned short* woutb = alloc((size_t)CMODEL * CMODEL * 2);
    unsigned short* Qb    = alloc((size_t)BATCH * NHEADS * TSEQ * DHEAD * 2);
    unsigned short* Kb    = alloc((size_t)BATCH * NHEADS * TSEQ * DHEAD * 2);
    unsigned short* Vt    = alloc((size_t)BATCH * NHEADS * TSEQ * DHEAD * 2);
    unsigned short* Ob    = alloc((size_t)MTOT * CMODEL * 2);

    int n4x = MTOT * CMODEL / 4;
    cvt_bf16_kernel<<<dim3((n4x + 255) / 256), 256, 0, stream>>>(x, xb, n4x);
    int n4q = NQKV * CMODEL / 4;
    cvt_bf16_kernel<<<dim3((n4q + 255) / 256), 256, 0, stream>>>(w_qkv, wqkvb, n4q);
    int n4o = CMODEL * CMODEL / 4;
    cvt_bf16_kernel<<<dim3((n4o + 255) / 256), 256, 0, stream>>>(w_out, woutb, n4o);

    gemm_qkv_kernel<<<dim3(NQKV / 128, MTOT / 128), 256, 0, stream>>>(
        xb, wqkvb, b_qkv, Qb, Kb, Vt);
    attn_kernel<<<dim3(32, BATCH * NHEADS), 256, 0, stream>>>(Qb, Kb, Vt, Ob);
    gemm_out_kernel<<<dim3(CMODEL / 128, MTOT / 128), 256, 0, stream>>>(
        Ob, woutb, b_out, out);
}